// Round 1
// baseline (13778.049 us; speedup 1.0000x reference)
//
#include <hip/hip_runtime.h>
#include <hip/hip_bf16.h>
#include <stdint.h>

typedef __attribute__((ext_vector_type(8))) short bf16x8;
typedef __attribute__((ext_vector_type(4))) float f32x4;
typedef __attribute__((ext_vector_type(4))) int int4v;

#define DD 512
#define HH 512
#define BB 32

__device__ __forceinline__ unsigned short f2bf(float f) {
  unsigned u = __float_as_uint(f);
  u += 0x7fffu + ((u >> 16) & 1u);
  return (unsigned short)(u >> 16);
}
__device__ __forceinline__ float sigf(float x) { return 1.f / (1.f + __expf(-x)); }
__device__ __forceinline__ float tanhfast(float x) {
  float e = __expf(fminf(fmaxf(2.f * x, -60.f), 60.f));
  return (e - 1.f) / (e + 1.f);
}

// ---- init kernels ----
__global__ void init_state(int* flags, unsigned* hbuf, const float* __restrict__ h0, int* L) {
  int i = blockIdx.x * blockDim.x + threadIdx.x;
  if (i < 1024) flags[i] = 0;
  if (i < 32) L[i] = 0;
  if (i < 16384) {
    int q = i & 255, m = (i >> 8) & 15, g = i >> 13;
    int b = g * 16 + m;
    unsigned lo = f2bf(h0[(size_t)b * HH + 2 * q]);
    unsigned hi = f2bf(h0[(size_t)b * HH + 2 * q + 1]);
    hbuf[i] = lo | (hi << 16);
  }
}

__global__ void init_idx(const int* __restrict__ t_idx, const int* __restrict__ b_idx,
                         int* rowstart, int* L, int total) {
  int r = blockIdx.x * blockDim.x + threadIdx.x;
  if (r >= total) return;
  int t = t_idx[r];
  if (r == 0 || t_idx[r - 1] != t) rowstart[t] = r;
  atomicMax(&L[b_idx[r]], t + 1);
}

// ---- main persistent recurrent kernel ----
// 64 blocks: group g = bid>>5 (16 seqs), slice k = bid&31 (hidden units [16k,16k+16))
__global__ __launch_bounds__(256, 1)
void lstm_main(const float* __restrict__ X, const float* __restrict__ h0,
               const float* __restrict__ c0, const float* __restrict__ w_ih,
               const float* __restrict__ w_hh, const float* __restrict__ b_ih,
               const float* __restrict__ b_hh, const int* __restrict__ rowstart,
               const int* __restrict__ L, int* flags, unsigned* hbuf,
               float* out, int total)
{
  const int tid = threadIdx.x;
  const int g = blockIdx.x >> 5;
  const int k = blockIdx.x & 31;
  const int lane = tid & 63;
  const int wave = tid >> 6;      // wave = gate type (i,f,g,o)
  const int ul = lane & 15;       // MFMA row (m) for A, col for B/C
  const int kc = lane >> 4;       // 0..3
  const int u0 = k * 16;
  const int j = wave * 512 + u0 + ul;   // gate column in [0,2048)

  __shared__ unsigned short h_st[16 * DD];   // 16KB, swizzled rows
  __shared__ unsigned short x_st[16 * DD];   // 16KB, swizzled rows
  __shared__ float gl[4][16][16];            // gates exchange
  __shared__ unsigned short hpub[16][16];    // h slice to publish

  // ---- preload weights into registers as bf16 B-fragments ----
  bf16x8 wfa[16], wfb[16];
#pragma unroll
  for (int kk = 0; kk < 16; kk++) {
    const float* pa = w_ih + (size_t)j * DD + kk * 32 + kc * 8;
    const float* pb = w_hh + (size_t)j * DD + kk * 32 + kc * 8;
    bf16x8 va, vb;
#pragma unroll
    for (int e = 0; e < 8; e++) { va[e] = (short)f2bf(pa[e]); vb[e] = (short)f2bf(pb[e]); }
    wfa[kk] = va; wfb[kk] = vb;
  }
  const float bias = b_ih[j] + b_hh[j];

  // ---- cell-thread mapping: thread -> (m, u) ----
  const int mC = tid >> 4;
  const int uC = tid & 15;
  const int bcell = g * 16 + mC;
  const int Lc = L[bcell];
  float c_reg = c0[(size_t)bcell * HH + u0 + uC];
  const float c0c = c_reg;
  const float h0c = h0[(size_t)bcell * HH + u0 + uC];

  int t0 = 0;
#pragma unroll
  for (int m = 0; m < 16; m++) t0 = max(t0, L[g * 16 + m]);
  t0 -= 1;
  const int S = t0 + 1;

  int* flagbase = flags + g * 512;            // 32 flags, stride 16 ints (64B)
  unsigned* hb_g = hbuf + g * 8192;           // [2 parity][16 m][256 pairs]
  const size_t hT_off = (size_t)total * HH;
  const size_t cT_off = hT_off + (size_t)BB * HH;

  char* hst_c = (char*)h_st;
  char* xst_c = (char*)x_st;
  const int swzW = (mC & 7) << 4;             // write-side XOR swizzle
  const int rbase = mC * 1024 + uC * 64;      // this thread's 64B region in stage
  const int arow = ul * 1024;
  const int aswz = (ul & 7) << 4;             // read-side XOR swizzle

  for (int s = 0, t = t0; s < S; s++, t--) {
    const bool act = (t < Lc);
    const int rst = rowstart[t];
    // 1) issue x loads early (independent of flags)
    f32x4 xr[8];
    if (act) {
      const f32x4* xp = (const f32x4*)(X + (size_t)(rst + bcell) * DD + uC * 32);
#pragma unroll
      for (int q = 0; q < 8; q++) xr[q] = xp[q];
    } else {
#pragma unroll
      for (int q = 0; q < 8; q++) xr[q] = (f32x4){0.f, 0.f, 0.f, 0.f};
    }
    // 2) wait for all 32 slices of h(step s)
    if (wave == 0) {
      for (;;) {
        int v = 0x7fffffff;
        if (lane < 32) v = __hip_atomic_load(flagbase + lane * 16, __ATOMIC_ACQUIRE, __HIP_MEMORY_SCOPE_AGENT);
        if (__all(v >= s)) break;
        __builtin_amdgcn_s_sleep(1);
      }
    }
    __syncthreads();
    // 3) gather h -> swizzled LDS (bypasses stale L1 via agent atomics)
    {
      unsigned* src = hb_g + ((s & 1) * 4096) + mC * 256 + uC * 16;
      unsigned hv[16];
#pragma unroll
      for (int q = 0; q < 16; q++) hv[q] = __hip_atomic_load(src + q, __ATOMIC_RELAXED, __HIP_MEMORY_SCOPE_AGENT);
#pragma unroll
      for (int c = 0; c < 4; c++) {
        int4v ch = {(int)hv[4 * c], (int)hv[4 * c + 1], (int)hv[4 * c + 2], (int)hv[4 * c + 3]};
        *(int4v*)(hst_c + ((rbase + c * 16) ^ swzW)) = ch;
      }
      // 4) convert+stage x
#pragma unroll
      for (int c = 0; c < 4; c++) {
        f32x4 a = xr[2 * c], b2 = xr[2 * c + 1];
        int4v ch = {(int)(f2bf(a[0]) | ((unsigned)f2bf(a[1]) << 16)),
                    (int)(f2bf(a[2]) | ((unsigned)f2bf(a[3]) << 16)),
                    (int)(f2bf(b2[0]) | ((unsigned)f2bf(b2[1]) << 16)),
                    (int)(f2bf(b2[2]) | ((unsigned)f2bf(b2[3]) << 16))};
        *(int4v*)(xst_c + ((rbase + c * 16) ^ swzW)) = ch;
      }
    }
    __syncthreads();
    // 5) gates = bias + x@Wih^T + h@Whh^T   (weights resident in VGPRs)
    f32x4 C = {bias, bias, bias, bias};
#pragma unroll
    for (int kk = 0; kk < 16; kk++) {
      bf16x8 A = *(const bf16x8*)(xst_c + ((arow + kk * 64 + kc * 16) ^ aswz));
      C = __builtin_amdgcn_mfma_f32_16x16x32_bf16(A, wfa[kk], C, 0, 0, 0);
    }
#pragma unroll
    for (int kk = 0; kk < 16; kk++) {
      bf16x8 A = *(const bf16x8*)(hst_c + ((arow + kk * 64 + kc * 16) ^ aswz));
      C = __builtin_amdgcn_mfma_f32_16x16x32_bf16(A, wfb[kk], C, 0, 0, 0);
    }
    // 6) exchange gates across waves (C/D layout: col=lane&15, row=(lane>>4)*4+r)
#pragma unroll
    for (int r = 0; r < 4; r++) gl[wave][kc * 4 + r][ul] = C[r];
    __syncthreads();
    // 7) cell math (fp32, c state thread-resident)
    float gi = gl[0][mC][uC], gf = gl[1][mC][uC], gg = gl[2][mC][uC], go = gl[3][mC][uC];
    float iv = sigf(gi), fv = sigf(gf), gv = tanhfast(gg), ov = sigf(go);
    float cn = fv * c_reg + iv * gv;
    float hn = ov * tanhfast(cn);
    float hp = act ? hn : h0c;     // inactive: keep publishing h0 (matches mask reset)
    c_reg = act ? cn : c0c;
    hpub[mC][uC] = f2bf(hp);
    __syncthreads();
    // 8) publish h slice + release flag
    if (tid < 128) {
      int mP = tid >> 3, pr = tid & 7;
      unsigned lo = hpub[mP][2 * pr], hi = hpub[mP][2 * pr + 1];
      __hip_atomic_store(hb_g + (((s + 1) & 1) * 4096) + mP * 256 + k * 8 + pr,
                         lo | (hi << 16), __ATOMIC_RELAXED, __HIP_MEMORY_SCOPE_AGENT);
    }
    __threadfence();
    __syncthreads();
    if (tid == 0)
      __hip_atomic_store(flagbase + k * 16, s + 1, __ATOMIC_RELEASE, __HIP_MEMORY_SCOPE_AGENT);
    // 9) output stores, off the critical path
    if (act) {
      out[(size_t)(rst + bcell) * HH + u0 + uC] = hn;
      if (t == 0) {
        out[hT_off + (size_t)bcell * HH + u0 + uC] = hn;
        out[cT_off + (size_t)bcell * HH + u0 + uC] = cn;
      }
    }
  }
}

extern "C" void kernel_launch(void* const* d_in, const int* in_sizes, int n_in,
                              void* d_out, int out_size, void* d_ws, size_t ws_size,
                              hipStream_t stream) {
  const float* X    = (const float*)d_in[0];
  const float* h0   = (const float*)d_in[1];
  const float* c0   = (const float*)d_in[2];
  const float* w_ih = (const float*)d_in[3];
  const float* w_hh = (const float*)d_in[4];
  const float* b_ih = (const float*)d_in[5];
  const float* b_hh = (const float*)d_in[6];
  const int* t_idx  = (const int*)d_in[7];
  const int* b_idx  = (const int*)d_in[8];
  int total = in_sizes[0] / DD;

  // ws layout: flags (1024 int) | hbuf (16384 u32) | rowstart (2048 int) | L (32 int)
  int* flags     = (int*)d_ws;
  unsigned* hbuf = (unsigned*)((char*)d_ws + 4096);
  int* rowstart  = (int*)((char*)d_ws + 4096 + 65536);
  int* L         = rowstart + 2048;

  hipLaunchKernelGGL(init_state, dim3(64), dim3(256), 0, stream, flags, hbuf, h0, L);
  hipLaunchKernelGGL(init_idx, dim3((total + 255) / 256), dim3(256), 0, stream,
                     t_idx, b_idx, rowstart, L, total);
  hipLaunchKernelGGL(lstm_main, dim3(64), dim3(256), 0, stream,
                     X, h0, c0, w_ih, w_hh, b_ih, b_hh, rowstart, L, flags, hbuf,
                     (float*)d_out, total);
}

// Round 2
// 7160.410 us; speedup vs baseline: 1.9242x; 1.9242x over previous
//
#include <hip/hip_runtime.h>
#include <hip/hip_bf16.h>
#include <stdint.h>

typedef __attribute__((ext_vector_type(8))) short bf16x8;
typedef __attribute__((ext_vector_type(4))) float f32x4;
typedef __attribute__((ext_vector_type(4))) int int4v;
typedef unsigned long long u64;

#define DD 512
#define HH 512
#define BB 32

__device__ __forceinline__ unsigned short f2bf(float f) {
  unsigned u = __float_as_uint(f);
  u += 0x7fffu + ((u >> 16) & 1u);
  return (unsigned short)(u >> 16);
}
__device__ __forceinline__ float sigf(float x) { return 1.f / (1.f + __expf(-x)); }
__device__ __forceinline__ float tanhfast(float x) {
  float e = __expf(fminf(fmaxf(2.f * x, -60.f), 60.f));
  return (e - 1.f) / (e + 1.f);
}

// ---- init kernels ----
__global__ void init_state(int* flags, unsigned* hbuf, const float* __restrict__ h0, int* L) {
  int i = blockIdx.x * blockDim.x + threadIdx.x;
  if (i < 1024) flags[i] = 0;
  if (i < 32) L[i] = 0;
  if (i < 16384) {
    int q = i & 255, m = (i >> 8) & 15, g = i >> 13;
    int b = g * 16 + m;
    unsigned lo = f2bf(h0[(size_t)b * HH + 2 * q]);
    unsigned hi = f2bf(h0[(size_t)b * HH + 2 * q + 1]);
    hbuf[i] = lo | (hi << 16);
  }
}

__global__ void init_idx(const int* __restrict__ t_idx, const int* __restrict__ b_idx,
                         int* rowstart, int* L, int total) {
  int r = blockIdx.x * blockDim.x + threadIdx.x;
  if (r >= total) return;
  int t = t_idx[r];
  if (r == 0 || t_idx[r - 1] != t) rowstart[t] = r;
  atomicMax(&L[b_idx[r]], t + 1);
}

// ---- main persistent recurrent kernel ----
// 64 blocks. bid = [k_hi(3b)][g(1b)][k_lo(2b)] so group 0 -> XCDs 0-3, group 1 -> XCDs 4-7.
__global__ __launch_bounds__(256, 1)
void lstm_main(const float* __restrict__ X, const float* __restrict__ h0,
               const float* __restrict__ c0, const float* __restrict__ w_ih,
               const float* __restrict__ w_hh, const float* __restrict__ b_ih,
               const float* __restrict__ b_hh, const int* __restrict__ rowstart,
               const int* __restrict__ L, int* flags, unsigned* hbuf,
               float* out, int total)
{
  const int tid = threadIdx.x;
  const int bid = blockIdx.x;
  const int g = (bid >> 2) & 1;
  const int k = (bid & 3) | ((bid >> 3) << 2);
  const int lane = tid & 63;
  const int wave = tid >> 6;      // wave = gate type (i,f,g,o)
  const int ul = lane & 15;       // MFMA row (m) for A, col for B/C
  const int kc = lane >> 4;       // 0..3
  const int u0 = k * 16;
  const int j = wave * 512 + u0 + ul;   // gate column in [0,2048)

  __shared__ unsigned short h_st[16 * DD];   // 16KB, swizzled rows
  __shared__ unsigned short x_st[16 * DD];   // 16KB, swizzled rows
  __shared__ float gl[4][16][16];            // gates exchange

  // ---- preload weights into registers as bf16 B-fragments ----
  bf16x8 wfa[16], wfb[16];
#pragma unroll
  for (int kk = 0; kk < 16; kk++) {
    const float* pa = w_ih + (size_t)j * DD + kk * 32 + kc * 8;
    const float* pb = w_hh + (size_t)j * DD + kk * 32 + kc * 8;
    bf16x8 va, vb;
#pragma unroll
    for (int e = 0; e < 8; e++) { va[e] = (short)f2bf(pa[e]); vb[e] = (short)f2bf(pb[e]); }
    wfa[kk] = va; wfb[kk] = vb;
  }
  const float bias = b_ih[j] + b_hh[j];

  // ---- cell-thread mapping: thread -> (m, u) ----
  const int mC = tid >> 4;
  const int uC = tid & 15;
  const int bcell = g * 16 + mC;
  const int Lc = L[bcell];
  float c_reg = c0[(size_t)bcell * HH + u0 + uC];
  const float c0c = c_reg;
  const float h0c = h0[(size_t)bcell * HH + u0 + uC];

  int t0 = 0;
#pragma unroll
  for (int m = 0; m < 16; m++) t0 = max(t0, L[g * 16 + m]);
  t0 -= 1;
  const int S = t0 + 1;

  int* flagbase = flags + g * 512;            // 32 flags, stride 16 ints (64B)
  unsigned* hb_g = hbuf + g * 8192;           // [2 parity][16 m][256 pairs]
  const size_t hT_off = (size_t)total * HH;
  const size_t cT_off = hT_off + (size_t)BB * HH;

  char* hst_c = (char*)h_st;
  char* xst_c = (char*)x_st;
  const int swzW = (mC & 7) << 4;             // write-side XOR swizzle
  const int rbase = mC * 1024 + uC * 64;      // this thread's 64B region in stage
  const int arow = ul * 1024;
  const int aswz = (ul & 7) << 4;             // read-side XOR swizzle

  for (int s = 0, t = t0; s < S; s++, t--) {
    const bool act = (t < Lc);
    const int rst = rowstart[t];
    // 1) x: load, convert, stage into LDS — all BEFORE the h wait (off critical path)
    {
      f32x4 xr[8];
      if (act) {
        const f32x4* xp = (const f32x4*)(X + (size_t)(rst + bcell) * DD + uC * 32);
#pragma unroll
        for (int q = 0; q < 8; q++) xr[q] = xp[q];
      } else {
#pragma unroll
        for (int q = 0; q < 8; q++) xr[q] = (f32x4){0.f, 0.f, 0.f, 0.f};
      }
#pragma unroll
      for (int c = 0; c < 4; c++) {
        f32x4 a = xr[2 * c], b2 = xr[2 * c + 1];
        int4v ch = {(int)(f2bf(a[0]) | ((unsigned)f2bf(a[1]) << 16)),
                    (int)(f2bf(a[2]) | ((unsigned)f2bf(a[3]) << 16)),
                    (int)(f2bf(b2[0]) | ((unsigned)f2bf(b2[1]) << 16)),
                    (int)(f2bf(b2[2]) | ((unsigned)f2bf(b2[3]) << 16))};
        *(int4v*)(xst_c + ((rbase + c * 16) ^ swzW)) = ch;
      }
    }
    // 2) wait for all 32 slices of h(step s): RELAXED polls only — no per-iteration
    //    cache invalidation. Gather loads below are sc0/sc1-coherent, so no acquire
    //    cache op is needed at all; __syncthreads orders compiler + waves.
    if (wave == 0) {
      for (;;) {
        int v = 0x7fffffff;
        if (lane < 32) v = __hip_atomic_load(flagbase + lane * 16, __ATOMIC_RELAXED, __HIP_MEMORY_SCOPE_AGENT);
        if (__all(v >= s)) break;
        __builtin_amdgcn_s_sleep(1);
      }
    }
    __syncthreads();
    // 3) gather h (u64 coherent loads) -> swizzled LDS
    {
      const u64* src = (const u64*)(hb_g + ((s & 1) * 4096)) + mC * 128 + uC * 8;
      u64 hv[8];
#pragma unroll
      for (int q = 0; q < 8; q++) hv[q] = __hip_atomic_load(src + q, __ATOMIC_RELAXED, __HIP_MEMORY_SCOPE_AGENT);
#pragma unroll
      for (int c = 0; c < 4; c++) {
        int4v ch = {(int)(unsigned)hv[2 * c], (int)(unsigned)(hv[2 * c] >> 32),
                    (int)(unsigned)hv[2 * c + 1], (int)(unsigned)(hv[2 * c + 1] >> 32)};
        *(int4v*)(hst_c + ((rbase + c * 16) ^ swzW)) = ch;
      }
    }
    __syncthreads();
    // 4) gates = bias + x@Wih^T + h@Whh^T   (weights resident in VGPRs)
    f32x4 C = {bias, bias, bias, bias};
#pragma unroll
    for (int kk = 0; kk < 16; kk++) {
      bf16x8 A = *(const bf16x8*)(xst_c + ((arow + kk * 64 + kc * 16) ^ aswz));
      C = __builtin_amdgcn_mfma_f32_16x16x32_bf16(A, wfa[kk], C, 0, 0, 0);
    }
#pragma unroll
    for (int kk = 0; kk < 16; kk++) {
      bf16x8 A = *(const bf16x8*)(hst_c + ((arow + kk * 64 + kc * 16) ^ aswz));
      C = __builtin_amdgcn_mfma_f32_16x16x32_bf16(A, wfb[kk], C, 0, 0, 0);
    }
    // 5) exchange gates across waves (C/D layout: col=lane&15, row=(lane>>4)*4+r)
#pragma unroll
    for (int r = 0; r < 4; r++) gl[wave][kc * 4 + r][ul] = C[r];
    __syncthreads();
    // 6) cell math (fp32, c state thread-resident)
    float gi = gl[0][mC][uC], gf = gl[1][mC][uC], gg = gl[2][mC][uC], go = gl[3][mC][uC];
    float iv = sigf(gi), fv = sigf(gf), gv = tanhfast(gg), ov = sigf(go);
    float cn = fv * c_reg + iv * gv;
    float hn = ov * tanhfast(cn);
    float hp = act ? hn : h0c;     // inactive: keep publishing h0 (matches mask reset)
    c_reg = act ? cn : c0c;
    // 7) pack h via shuffles (no LDS round trip) and publish as u64 coherent stores
    {
      unsigned hbf = f2bf(hp);
      unsigned v1 = __shfl_down(hbf, 1);
      unsigned pair = (hbf & 0xffffu) | (v1 << 16);
      unsigned p2 = __shfl_down(pair, 2);
      if ((uC & 3) == 0) {
        u64 val = (u64)pair | ((u64)p2 << 32);
        u64* dst = (u64*)(hb_g + (((s + 1) & 1) * 4096)) + mC * 128 + k * 4 + (uC >> 2);
        __hip_atomic_store(dst, val, __ATOMIC_RELAXED, __HIP_MEMORY_SCOPE_AGENT);
      }
    }
    // 8) release: drain this thread's coherent stores, barrier joins all threads,
    //    then a relaxed flag store. No L2 writeback/invalidate anywhere.
    asm volatile("s_waitcnt vmcnt(0)" ::: "memory");
    __syncthreads();
    if (tid == 0)
      __hip_atomic_store(flagbase + k * 16, s + 1, __ATOMIC_RELAXED, __HIP_MEMORY_SCOPE_AGENT);
    // 9) output stores, off the critical path
    if (act) {
      out[(size_t)(rst + bcell) * HH + u0 + uC] = hn;
      if (t == 0) {
        out[hT_off + (size_t)bcell * HH + u0 + uC] = hn;
        out[cT_off + (size_t)bcell * HH + u0 + uC] = cn;
      }
    }
  }
}

extern "C" void kernel_launch(void* const* d_in, const int* in_sizes, int n_in,
                              void* d_out, int out_size, void* d_ws, size_t ws_size,
                              hipStream_t stream) {
  const float* X    = (const float*)d_in[0];
  const float* h0   = (const float*)d_in[1];
  const float* c0   = (const float*)d_in[2];
  const float* w_ih = (const float*)d_in[3];
  const float* w_hh = (const float*)d_in[4];
  const float* b_ih = (const float*)d_in[5];
  const float* b_hh = (const float*)d_in[6];
  const int* t_idx  = (const int*)d_in[7];
  const int* b_idx  = (const int*)d_in[8];
  int total = in_sizes[0] / DD;

  // ws layout: flags (1024 int) | hbuf (16384 u32) | rowstart (2048 int) | L (32 int)
  int* flags     = (int*)d_ws;
  unsigned* hbuf = (unsigned*)((char*)d_ws + 4096);
  int* rowstart  = (int*)((char*)d_ws + 4096 + 65536);
  int* L         = rowstart + 2048;

  hipLaunchKernelGGL(init_state, dim3(64), dim3(256), 0, stream, flags, hbuf, h0, L);
  hipLaunchKernelGGL(init_idx, dim3((total + 255) / 256), dim3(256), 0, stream,
                     t_idx, b_idx, rowstart, L, total);
  hipLaunchKernelGGL(lstm_main, dim3(64), dim3(256), 0, stream,
                     X, h0, c0, w_ih, w_hh, b_ih, b_hh, rowstart, L, flags, hbuf,
                     (float*)d_out, total);
}